// Round 6
// baseline (259.888 us; speedup 1.0000x reference)
//
#include <hip/hip_runtime.h>
#include <math.h>

// CTC batch cost (Keras ctc_batch_cost), gfx950. B=256,T=512,V=256,L=64,S=129.
//
// *** DIAGNOSTIC ROUND: REP=4 in-kernel repeats of the identical R5 DP so
// ctc_kernel rises above the harness fillBuffer dispatches in rocprof and we
// finally see its VALUBusy / FETCH_SIZE / VGPR / LDS-conflict counters.
// Only rep 0's result is written; math identical to R5 (absmax 0.0). ***
//
// Structure (R5): one block = one batch element = 2 waves.
//   wave 1 (loader): streams blank + per-lane label probs per 32-step chunk
//     global -> compact LDS ring (4 buffers), 2 chunks ahead.
//   wave 0 (DP): per chunk reads 64 values LDS->reg, then 32 register-only
//     DP steps (scaled forward, per-lane pow2 rescale, DPP wave_shr:1).

#define BB   256
#define TI   512
#define VV   256
#define LL   64
#define CH   32
#define NCH  (TI / CH)          // 16 chunks
#define REP  4
#define EPSF 1e-7f
#define LN2F 0.6931471805599453f

#if __has_builtin(__builtin_amdgcn_logf)
__device__ __forceinline__ float flog2(float x) { return __builtin_amdgcn_logf(x); }
#else
__device__ __forceinline__ float flog2(float x) { return __log2f(x); }
#endif

template <int CTRL>
__device__ __forceinline__ float dppf(float oldv, float v) {
    return __int_as_float(__builtin_amdgcn_update_dpp(
        __float_as_int(oldv), __float_as_int(v), CTRL, 0xF, 0xF, false));
}
// lane i <- lane i-1; lane 0 <- 0.0f  (v_mov_b32_dpp wave_shr:1)
__device__ __forceinline__ float shup0(float x) { return dppf<0x138>(0.0f, x); }

struct DP {
    float a0, a1, a128;   // scaled alphas (a128 meaningful on lane 63)
    float C;              // log2 of this lane's scale (integer-valued float)
    float f, fs;          // 2^(C[l-1]-C[l]), and f*skip
    float skipf;
    int   lane;
};

__device__ __forceinline__ void rescale(DP& d) {
    float m  = fmaxf(fmaxf(d.a0, d.a1), d.a128);     // v_max3
    int   mi    = __float_as_int(m);                 // m >= 0
    int   ebits = mi & 0x7f800000;
    bool  dead  = (ebits == 0);                      // m < 2^-126 (0/denorm)
    float s = __int_as_float((254 << 23) - ebits);   // exact 2^-E
    s = dead ? 1.0f : s;
    d.a0 *= s; d.a1 *= s; d.a128 *= s;               // exact pow2 scaling
    float Ei  = (float)((mi >> 23) - 127);           // E (unused if dead)
    float Cm1 = shup0(d.C);                          // left C (pre-update)
    d.C = dead ? Cm1 : (d.C + Ei);                   // dead lanes adopt
    float Cm1b = shup0(d.C);                         // left C (post-update)
    int dCi = (int)(Cm1b - d.C);                     // exact integer
    int e = dCi + 127;
    e = e < 0 ? 0 : (e > 254 ? 254 : e);             // clamp: f=0 / f=2^127
    float fn = __int_as_float(e << 23);              // 2^dCi
    d.f  = (d.lane == 0) ? 0.0f : fn;                // alpha[-1] == 0
    d.fs = d.f * d.skipf;
}

__device__ __forceinline__ void dp_step(DP& d, float pb, float pl) {
    float pa1 = shup0(d.a1);                         // alpha[2L-1], prev scale
    float s01 = d.a0 + d.a1;
    float na0   = fmaf(pa1, d.f,  d.a0) * pb;        // (a0 + pa1*f)*pb
    float na1   = fmaf(pa1, d.fs, s01)  * pl;        // (a1+a0+skip*pa1*f)*pl
    float na128 = (d.a128 + d.a1) * pb;              // lane 63
    d.a0 = na0; d.a1 = na1; d.a128 = na128;
}

template <bool PA, bool FIRST>
__device__ __forceinline__ void dp_chunk(DP& d, const float (&pb)[CH],
                                         const float (&pl)[CH]) {
    #pragma unroll
    for (int tt = 0; tt < CH; ++tt) {
        if (FIRST && tt == 0) {
            d.a0 = (d.lane == 0) ? pb[0] : 0.0f;     // alpha0: s=0, s=1 only
            d.a1 = (d.lane == 0) ? pl[0] : 0.0f;
        } else {
            dp_step(d, pb[tt], pl[tt]);
        }
        if (PA || (tt & 7) == 7) rescale(d);
    }
}

// loader wave: fetch chunk cc's blank col + per-lane label cols -> LDS
__device__ __forceinline__ void fill_chunk(const float* __restrict__ src,
                                           int lab, int cc, int lane,
                                           float* __restrict__ pbuf,
                                           float* __restrict__ lbuf) {
    const float* rowbase = src + (size_t)cc * CH * VV;
    const int r = lane & 31;
    float bv = rowbase[r * VV + (VV - 1)];
    float lv[CH];
    #pragma unroll
    for (int i = 0; i < CH; ++i)
        lv[i] = rowbase[i * VV + lab];
    if (lane < 32) pbuf[r] = bv + EPSF;
    #pragma unroll
    for (int i = 0; i < CH; ++i)
        lbuf[i * 64 + lane] = lv[i] + EPSF;
}

__global__ __launch_bounds__(128) void ctc_kernel(
        const int* __restrict__ y_true,
        const float* __restrict__ y_pred,
        float* __restrict__ out) {
    __shared__ float pbuf[4][CH];          // blank prob ring
    __shared__ float lbuf[4][CH * 64];     // label prob ring (32 KB)

    const int b    = blockIdx.x;
    const int tid  = threadIdx.x;
    const int lane = tid & 63;
    const int wave = tid >> 6;
    const float* src = y_pred + (size_t)b * TI * VV;

    const int lab = y_true[b * LL + lane];
    float skipf;
    {
        const int prevLab = __shfl_up(lab, 1);
        skipf = (lane == 0 || lab != prevLab) ? 1.0f : 0.0f;
    }

    float acc = 0.0f;

    for (int rep = 0; rep < REP; ++rep) {
        DP d;
        d.lane  = lane;
        d.skipf = skipf;
        d.a0 = 0.0f; d.a1 = 0.0f; d.a128 = 0.0f;
        d.C = 0.0f; d.f = 0.0f; d.fs = 0.0f;

        if (wave == 1) {
            fill_chunk(src, lab, 0, lane, pbuf[0], lbuf[0]);
            fill_chunk(src, lab, 1, lane, pbuf[1], lbuf[1]);
        }
        __syncthreads();

        for (int c = 0; c < NCH; ++c) {
            if (wave == 1) {
                if (c + 2 < NCH)
                    fill_chunk(src, lab, c + 2, lane,
                               pbuf[(c + 2) & 3], lbuf[(c + 2) & 3]);
            } else {
                float pb[CH], pl[CH];
                const float* pp = pbuf[c & 3];
                const float* ll = lbuf[c & 3] + lane;
                #pragma unroll
                for (int i = 0; i < CH; ++i) {
                    pb[i] = pp[i];             // broadcast read
                    pl[i] = ll[i * 64];        // conflict-free (2-way)
                }
                if (c == 0)      dp_chunk<true,  true >(d, pb, pl);
                else if (c < 4)  dp_chunk<true,  false>(d, pb, pl);  // t<128
                else             dp_chunk<false, false>(d, pb, pl);
            }
            __syncthreads();
        }

        if (wave == 0 && lane == 63) {
            float tail = fmaxf(d.a128 + d.a1, 1e-37f);
            float val  = -LN2F * (d.C + flog2(tail));
            acc += (rep == 0) ? val : 0.0f;    // keep rep 0 only; forces
        }                                      // re-computation each rep
        __syncthreads();                       // keep reps fully ordered
    }

    if (wave == 0 && lane == 63) out[b] = acc;
}

extern "C" void kernel_launch(void* const* d_in, const int* in_sizes, int n_in,
                              void* d_out, int out_size, void* d_ws, size_t ws_size,
                              hipStream_t stream) {
    const int*   y_true = (const int*)d_in[0];
    const float* y_pred = (const float*)d_in[1];
    float*       out    = (float*)d_out;
    ctc_kernel<<<dim3(BB), dim3(128), 0, stream>>>(y_true, y_pred, out);
}

// Round 7
// 196.010 us; speedup vs baseline: 1.3259x; 1.3259x over previous
//
#include <hip/hip_runtime.h>
#include <math.h>

// CTC batch cost (Keras ctc_batch_cost), gfx950. B=256,T=512,V=256,L=64,S=129.
//
// One block = one batch element = 2 waves:
//   wave 1 (loader): stages FULL 1 KB rows of y_pred via global_load_lds
//     (16 B/lane, one instruction per row, no VGPR round-trip) into a
//     4-chunk LDS ring (chunk = 32 timesteps x 256 floats = 32 KB; ring =
//     128 KB), staying 2 chunks ahead. Its only wait is the compiler's
//     vmcnt(0) drain at its own barrier - issued-to-drain spans a whole
//     iteration, overlapped with the DP wave's compute.
//   wave 0 (DP): per chunk reads 32 blank probs (lane-uniform broadcast
//     ds_read) + 32 per-lane label probs (random-bank gather) from LDS,
//     then 32 register-only DP steps. Zero outstanding vmem -> clean
//     barriers, no waitcnt aliasing hazards.
//
// DP math identical to R4/R5 (absmax 0.0 verified): scaled forward
// algorithm in linear space, per-lane power-of-two rescaling (exact
// exponent-bit arithmetic), cross-lane alpha[2L-1] via DPP wave_shr:1,
// phase A (t<128, frontier active w/ skip transitions = 1 lane/step)
// rescales EVERY step, phase B every 8 steps. No transcendentals in loop.

#define BB   256
#define TI   512
#define VV   256
#define LL   64
#define CH   32
#define NCH  (TI / CH)          // 16 chunks
#define RING 4
#define EPSF 1e-7f
#define LN2F 0.6931471805599453f

#if __has_builtin(__builtin_amdgcn_logf)
__device__ __forceinline__ float flog2(float x) { return __builtin_amdgcn_logf(x); }
#else
__device__ __forceinline__ float flog2(float x) { return __log2f(x); }
#endif

template <int CTRL>
__device__ __forceinline__ float dppf(float oldv, float v) {
    return __int_as_float(__builtin_amdgcn_update_dpp(
        __float_as_int(oldv), __float_as_int(v), CTRL, 0xF, 0xF, false));
}
// lane i <- lane i-1; lane 0 <- 0.0f  (v_mov_b32_dpp wave_shr:1)
__device__ __forceinline__ float shup0(float x) { return dppf<0x138>(0.0f, x); }

struct DP {
    float a0, a1, a128;   // scaled alphas (a128 meaningful on lane 63)
    float C;              // log2 of this lane's scale (integer-valued float)
    float f, fs;          // 2^(C[l-1]-C[l]), and f*skip
    float skipf;
    int   lane;
};

__device__ __forceinline__ void rescale(DP& d) {
    float m  = fmaxf(fmaxf(d.a0, d.a1), d.a128);     // v_max3
    int   mi    = __float_as_int(m);                 // m >= 0
    int   ebits = mi & 0x7f800000;
    bool  dead  = (ebits == 0);                      // m < 2^-126 (0/denorm)
    float s = __int_as_float((254 << 23) - ebits);   // exact 2^-E
    s = dead ? 1.0f : s;
    d.a0 *= s; d.a1 *= s; d.a128 *= s;               // exact pow2 scaling
    float Ei  = (float)((mi >> 23) - 127);           // E (unused if dead)
    float Cm1 = shup0(d.C);                          // left C (pre-update)
    d.C = dead ? Cm1 : (d.C + Ei);                   // dead lanes adopt
    float Cm1b = shup0(d.C);                         // left C (post-update)
    int dCi = (int)(Cm1b - d.C);                     // exact integer
    int e = dCi + 127;
    e = e < 0 ? 0 : (e > 254 ? 254 : e);             // clamp: f=0 / f=2^127
    float fn = __int_as_float(e << 23);              // 2^dCi
    d.f  = (d.lane == 0) ? 0.0f : fn;                // alpha[-1] == 0
    d.fs = d.f * d.skipf;
}

__device__ __forceinline__ void dp_step(DP& d, float pb, float pl) {
    float pa1 = shup0(d.a1);                         // alpha[2L-1], prev scale
    float s01 = d.a0 + d.a1;
    float na0   = fmaf(pa1, d.f,  d.a0) * pb;        // (a0 + pa1*f)*pb
    float na1   = fmaf(pa1, d.fs, s01)  * pl;        // (a1+a0+skip*pa1*f)*pl
    float na128 = (d.a128 + d.a1) * pb;              // lane 63
    d.a0 = na0; d.a1 = na1; d.a128 = na128;
}

template <bool PA, bool FIRST>
__device__ __forceinline__ void dp_chunk(DP& d, const float (&pb)[CH],
                                         const float (&pl)[CH]) {
    #pragma unroll
    for (int tt = 0; tt < CH; ++tt) {
        if (FIRST && tt == 0) {
            d.a0 = (d.lane == 0) ? pb[0] : 0.0f;     // alpha0: s=0, s=1 only
            d.a1 = (d.lane == 0) ? pl[0] : 0.0f;
        } else {
            dp_step(d, pb[tt], pl[tt]);
        }
        if (PA || (tt & 7) == 7) rescale(d);
    }
}

// loader wave: stage chunk cc's 32 full rows global -> LDS ring slot.
// One global_load_lds per row: 64 lanes x 16 B = 1024 B = one row.
__device__ __forceinline__ void stage_chunk(const float* __restrict__ src,
                                            int cc, int lane,
                                            float* __restrict__ lslot) {
    const float* g = src + (size_t)cc * CH * VV + lane * 4;   // 16 B / lane
    #pragma unroll
    for (int r = 0; r < CH; ++r) {
        __builtin_amdgcn_global_load_lds(
            (const __attribute__((address_space(1))) void*)(g + r * VV),
            (__attribute__((address_space(3))) void*)(lslot + r * VV),
            16, 0, 0);
    }
}

__global__ __launch_bounds__(128) void ctc_kernel(
        const int* __restrict__ y_true,
        const float* __restrict__ y_pred,
        float* __restrict__ out) {
    __shared__ float ring[RING][CH * VV];   // 4 x 32 KB = 128 KB

    const int b    = blockIdx.x;
    const int tid  = threadIdx.x;
    const int lane = tid & 63;
    const int wave = tid >> 6;
    const float* src = y_pred + (size_t)b * TI * VV;

    const int lab = y_true[b * LL + lane];

    DP d;
    d.lane = lane;
    {
        const int prevLab = __shfl_up(lab, 1);
        d.skipf = (lane == 0 || lab != prevLab) ? 1.0f : 0.0f;
    }
    d.a0 = 0.0f; d.a1 = 0.0f; d.a128 = 0.0f;
    d.C = 0.0f; d.f = 0.0f; d.fs = 0.0f;

    // prologue: loader stages chunks 0 and 1
    if (wave == 1) {
        stage_chunk(src, 0, lane, ring[0]);
        stage_chunk(src, 1, lane, ring[1]);
    }
    __syncthreads();   // loader's vmcnt(0) drain happens here (its wave only)

    for (int c = 0; c < NCH; ++c) {
        if (wave == 1) {
            if (c + 2 < NCH)
                stage_chunk(src, c + 2, lane, ring[(c + 2) & (RING - 1)]);
        } else {
            // LDS -> registers for this chunk
            const float* base = ring[c & (RING - 1)];
            float pb[CH], pl[CH];
            #pragma unroll
            for (int i = 0; i < CH; ++i) {
                pb[i] = base[i * VV + (VV - 1)] + EPSF;  // uniform broadcast
                pl[i] = base[i * VV + lab]      + EPSF;  // per-lane gather
            }
            if (c == 0)      dp_chunk<true,  true >(d, pb, pl);
            else if (c < 4)  dp_chunk<true,  false>(d, pb, pl);  // t < 128
            else             dp_chunk<false, false>(d, pb, pl);
        }
        __syncthreads();
    }

    // loss = -ln2 * (C + log2(alpha[128] + alpha[127])), lane 63 of DP wave
    if (wave == 0 && lane == 63) {
        float tail = fmaxf(d.a128 + d.a1, 1e-37f);
        out[b] = -LN2F * (d.C + flog2(tail));
    }
}

extern "C" void kernel_launch(void* const* d_in, const int* in_sizes, int n_in,
                              void* d_out, int out_size, void* d_ws, size_t ws_size,
                              hipStream_t stream) {
    const int*   y_true = (const int*)d_in[0];
    const float* y_pred = (const float*)d_in[1];
    float*       out    = (float*)d_out;
    ctc_kernel<<<dim3(BB), dim3(128), 0, stream>>>(y_true, y_pred, out);
}

// Round 8
// 193.970 us; speedup vs baseline: 1.3398x; 1.0105x over previous
//
#include <hip/hip_runtime.h>
#include <math.h>

// CTC batch cost (Keras ctc_batch_cost), gfx950. B=256,T=512,V=256,L=64,S=129.
//
// One block = one batch element = 2 waves, NO barriers in the main loop:
//   wave 1 (loader): stages 16-row chunks (16 KB) of y_pred via
//     global_load_lds (16 B/lane, coalesced full rows) into an 8-slot LDS
//     ring. Keeps 2-3 chunks (<=48 loads) in flight with manual
//     s_waitcnt vmcnt(32) -- never drains to 0 until the tail -- and
//     publishes a monotone `produced` chunk-counter in LDS after each
//     chunk is confirmed resident. Ring overwrite is guarded by polling
//     the DP wave's `consumed` counter.
//   wave 0 (DP): polls `produced`, reads 16 blank probs (broadcast) +
//     16 per-lane label probs (gather) LDS->reg, waits lgkmcnt(0), bumps
//     `consumed`, then runs 16 register-only DP steps.
// This removes the compiler's vmcnt(0)-before-s_barrier drain that capped
// the R7 loader at ~1 chunk of memory-level parallelism (~2 TB/s).
//
// DP math identical to R4-R7 (absmax 0.0 verified): scaled forward
// algorithm in linear space, per-lane power-of-two rescaling (exact
// exponent-bit arithmetic), cross-lane alpha[2L-1] via DPP wave_shr:1,
// phase A (t<128, frontier active) rescales every step, phase B every
// 8 steps. No transcendentals in the loop.

#define BB   256
#define TI   512
#define VV   256
#define LL   64
#define CH   16
#define NCH  (TI / CH)          // 32 chunks
#define RING 8                  // 8 x 16 KB = 128 KB LDS ring
#define EPSF 1e-7f
#define LN2F 0.6931471805599453f

#define CFENCE() asm volatile("" ::: "memory")

#if __has_builtin(__builtin_amdgcn_logf)
__device__ __forceinline__ float flog2(float x) { return __builtin_amdgcn_logf(x); }
#else
__device__ __forceinline__ float flog2(float x) { return __log2f(x); }
#endif

template <int CTRL>
__device__ __forceinline__ float dppf(float oldv, float v) {
    return __int_as_float(__builtin_amdgcn_update_dpp(
        __float_as_int(oldv), __float_as_int(v), CTRL, 0xF, 0xF, false));
}
// lane i <- lane i-1; lane 0 <- 0.0f  (v_mov_b32_dpp wave_shr:1)
__device__ __forceinline__ float shup0(float x) { return dppf<0x138>(0.0f, x); }

struct DP {
    float a0, a1, a128;   // scaled alphas (a128 meaningful on lane 63)
    float C;              // log2 of this lane's scale (integer-valued float)
    float f, fs;          // 2^(C[l-1]-C[l]), and f*skip
    float skipf;
    int   lane;
};

__device__ __forceinline__ void rescale(DP& d) {
    float m  = fmaxf(fmaxf(d.a0, d.a1), d.a128);     // v_max3
    int   mi    = __float_as_int(m);                 // m >= 0
    int   ebits = mi & 0x7f800000;
    bool  dead  = (ebits == 0);                      // m < 2^-126 (0/denorm)
    float s = __int_as_float((254 << 23) - ebits);   // exact 2^-E
    s = dead ? 1.0f : s;
    d.a0 *= s; d.a1 *= s; d.a128 *= s;               // exact pow2 scaling
    float Ei  = (float)((mi >> 23) - 127);           // E (unused if dead)
    float Cm1 = shup0(d.C);                          // left C (pre-update)
    d.C = dead ? Cm1 : (d.C + Ei);                   // dead lanes adopt
    float Cm1b = shup0(d.C);                         // left C (post-update)
    int dCi = (int)(Cm1b - d.C);                     // exact integer
    int e = dCi + 127;
    e = e < 0 ? 0 : (e > 254 ? 254 : e);             // clamp: f=0 / f=2^127
    float fn = __int_as_float(e << 23);              // 2^dCi
    d.f  = (d.lane == 0) ? 0.0f : fn;                // alpha[-1] == 0
    d.fs = d.f * d.skipf;
}

__device__ __forceinline__ void dp_step(DP& d, float pb, float pl) {
    float pa1 = shup0(d.a1);                         // alpha[2L-1], prev scale
    float s01 = d.a0 + d.a1;
    float na0   = fmaf(pa1, d.f,  d.a0) * pb;        // (a0 + pa1*f)*pb
    float na1   = fmaf(pa1, d.fs, s01)  * pl;        // (a1+a0+skip*pa1*f)*pl
    float na128 = (d.a128 + d.a1) * pb;              // lane 63
    d.a0 = na0; d.a1 = na1; d.a128 = na128;
}

template <bool PA, bool FIRST>
__device__ __forceinline__ void dp_chunk(DP& d, const float (&pb)[CH],
                                         const float (&pl)[CH]) {
    #pragma unroll
    for (int tt = 0; tt < CH; ++tt) {
        if (FIRST && tt == 0) {
            d.a0 = (d.lane == 0) ? pb[0] : 0.0f;     // alpha0: s=0, s=1 only
            d.a1 = (d.lane == 0) ? pl[0] : 0.0f;
        } else {
            dp_step(d, pb[tt], pl[tt]);
        }
        if (PA || (tt & 7) == 7) rescale(d);
    }
}

// stage chunk n's 16 full rows global -> LDS slot (one 16B/lane DMA per row)
__device__ __forceinline__ void stage_chunk(const float* __restrict__ src,
                                            int n, int lane,
                                            float* __restrict__ slot) {
    const float* g = src + (size_t)n * CH * VV + lane * 4;
    #pragma unroll
    for (int r = 0; r < CH; ++r) {
        __builtin_amdgcn_global_load_lds(
            (const __attribute__((address_space(1))) void*)(g + r * VV),
            (__attribute__((address_space(3))) void*)(slot + r * VV),
            16, 0, 0);
    }
}

__global__ __launch_bounds__(128) void ctc_kernel(
        const int* __restrict__ y_true,
        const float* __restrict__ y_pred,
        float* __restrict__ out) {
    __shared__ float ring[RING][CH * VV];   // 128 KB
    __shared__ int   prod_cnt, cons_cnt;

    const int b    = blockIdx.x;
    const int tid  = threadIdx.x;
    const int lane = tid & 63;
    const int wave = tid >> 6;
    const float* src = y_pred + (size_t)b * TI * VV;

    volatile int* vp = &prod_cnt;
    volatile int* vc = &cons_cnt;

    const int lab = y_true[b * LL + lane];

    if (tid == 0) { prod_cnt = 0; cons_cnt = 0; }
    __syncthreads();                        // only barrier in the kernel

    if (wave == 1) {
        // ---------------- loader wave ----------------
        for (int n = 0; n < NCH; ++n) {
            if (n >= RING) {                // slot reuse: chunk n-RING read?
                while (*vc < n - (RING - 1)) { }
                CFENCE();
            }
            stage_chunk(src, n, lane, ring[n & (RING - 1)]);
            if (n >= 2) {
                // allow the 2 newest chunks (32 loads) to stay in flight;
                // chunk n-2 is now resident -> publish produced = n-1
                asm volatile("s_waitcnt vmcnt(32)" ::: "memory");
                if (lane == 0) *vp = n - 1;
            }
        }
        asm volatile("s_waitcnt vmcnt(16)" ::: "memory");
        if (lane == 0) *vp = NCH - 1;       // chunk 30 resident
        asm volatile("s_waitcnt vmcnt(0)" ::: "memory");
        if (lane == 0) *vp = NCH;           // all resident
    } else {
        // ---------------- DP wave ----------------
        DP d;
        d.lane = lane;
        {
            const int prevLab = __shfl_up(lab, 1);
            d.skipf = (lane == 0 || lab != prevLab) ? 1.0f : 0.0f;
        }
        d.a0 = 0.0f; d.a1 = 0.0f; d.a128 = 0.0f;
        d.C = 0.0f; d.f = 0.0f; d.fs = 0.0f;

        for (int c = 0; c < NCH; ++c) {
            while (*vp < c + 1) { }         // chunk c resident?
            CFENCE();
            const float* base = ring[c & (RING - 1)];
            float pb[CH], pl[CH];
            #pragma unroll
            for (int i = 0; i < CH; ++i) {
                pb[i] = base[i * VV + (VV - 1)] + EPSF;  // broadcast
                pl[i] = base[i * VV + lab]      + EPSF;  // per-lane gather
            }
            asm volatile("s_waitcnt lgkmcnt(0)" ::: "memory");
            if (lane == 0) *vc = c + 1;     // slot free for loader
            CFENCE();
            if (c == 0)      dp_chunk<true,  true >(d, pb, pl);
            else if (c < 8)  dp_chunk<true,  false>(d, pb, pl);  // t < 128
            else             dp_chunk<false, false>(d, pb, pl);
        }

        // loss = -ln2 * (C + log2(alpha[128] + alpha[127])), lane 63
        if (lane == 63) {
            float tail = fmaxf(d.a128 + d.a1, 1e-37f);
            out[b] = -LN2F * (d.C + flog2(tail));
        }
    }
}

extern "C" void kernel_launch(void* const* d_in, const int* in_sizes, int n_in,
                              void* d_out, int out_size, void* d_ws, size_t ws_size,
                              hipStream_t stream) {
    const int*   y_true = (const int*)d_in[0];
    const float* y_pred = (const float*)d_in[1];
    float*       out    = (float*)d_out;
    ctc_kernel<<<dim3(BB), dim3(128), 0, stream>>>(y_true, y_pred, out);
}